// Round 10
// baseline (343.721 us; speedup 1.0000x reference)
//
#include <hip/hip_runtime.h>

#define N_NODES_C 50000
#define N_EDGES_C 800000
#define N_EDGES2_C (2 * N_EDGES_C)
#define D 128
#define NSHARD 8
#define SCAP 32  // slots per (row, xcd) cell; load ~Poisson(4), P(>32) ~ 1e-19

static __device__ __forceinline__ unsigned short f2bf(float f) {
  unsigned u = __float_as_uint(f);
  u += 0x7fff + ((u >> 16) & 1);  // round-to-nearest-even
  return (unsigned short)(u >> 16);
}
static __device__ __forceinline__ float bf_lo(unsigned u) {
  return __uint_as_float(u << 16);
}
static __device__ __forceinline__ float bf_hi(unsigned u) {
  return __uint_as_float(u & 0xffff0000u);
}

// Physical XCD id (0..7), wave-uniform. HW-verified on gfx950 (XCC_ID).
// Correctness does not depend on the value — it only steers L2 locality.
static __device__ __forceinline__ int xcd_id() {
  int v;
  asm volatile("s_getreg_b32 %0, hwreg(HW_REG_XCC_ID, 0, 4)" : "=s"(v));
  return v & (NSHARD - 1);
}

// ---------------------------------------------------------------------------
// Kernel 1: alpha[i] = sigmoid(dot(x[i], alpha_w) + alpha_b), wave per node.
// ---------------------------------------------------------------------------
__global__ __launch_bounds__(256) void alpha_kernel(
    const float* __restrict__ x,
    const float* __restrict__ aw,
    const float* __restrict__ ab,
    float* __restrict__ alpha_out,
    float* __restrict__ alpha_ws,
    int n) {
  int wave = (int)((blockIdx.x * blockDim.x + threadIdx.x) >> 6);
  int lane = threadIdx.x & 63;
  if (wave >= n) return;
  const float* xr = x + (size_t)wave * D;
  float s = xr[lane] * aw[lane] + xr[lane + 64] * aw[lane + 64];
  #pragma unroll
  for (int off = 32; off > 0; off >>= 1)
    s += __shfl_down(s, off);
  if (lane == 0) {
    float a = 1.0f / (1.0f + __expf(-(s + ab[0])));
    alpha_out[wave] = a;
    alpha_ws[wave] = a;
  }
}

// ---------------------------------------------------------------------------
// Kernel 2: fill — XCD-sharded scatter. Cell (row, xcd) = 32 packed slots
// (128 B, line-aligned); all writes to a cell (and its cursor) come from one
// XCD -> no cross-XCD line ping-pong -> writebacks ~ lines touched (~26 MB),
// not ~1 line per write (~100 MB, measured R4/R8/R9).
// Packed slot: col:16 | bf16(gate-scaled val):16.
// ---------------------------------------------------------------------------
__global__ __launch_bounds__(256) void fill_kernel(
    const int* __restrict__ lp_rows, const int* __restrict__ lp_cols,
    const float* __restrict__ lp_vals,
    const int* __restrict__ hp_rows, const int* __restrict__ hp_cols,
    const float* __restrict__ hp_vals,
    const float* __restrict__ alpha,
    int* __restrict__ rcursor,      // [N][8], zeroed before launch
    unsigned* __restrict__ pairs) { // [N][8][SCAP]
  int e = blockIdx.x * 256 + threadIdx.x;
  if (e >= N_EDGES2_C) return;
  int xcc = xcd_id();
  int r, c;
  float v;
  if (e < N_EDGES_C) {
    r = lp_rows[e];
    c = lp_cols[e];
    v = lp_vals[e] * alpha[r];
  } else {
    int i = e - N_EDGES_C;
    r = hp_rows[i];
    c = hp_cols[i];
    v = hp_vals[i] * (1.0f - alpha[r]);
  }
  unsigned pk = (unsigned)c | ((unsigned)f2bf(v) << 16);
  int p = atomicAdd(&rcursor[(r << 3) + xcc], 1);
  if (p < SCAP) pairs[((size_t)r << 8) + (xcc << 5) + p] = pk;
}

// ---------------------------------------------------------------------------
// Kernel 3: gemm_y: y = x @ W^T, bf16, paired packing: word d of a row =
// (bf16 dim d, bf16 dim d+64). Thread tj owns dims {2tj,2tj+1,2tj+64,2tj+65}.
// ---------------------------------------------------------------------------
#define GNODES 64
#define GP 16
#define LDP 132

__global__ __launch_bounds__(256) void gemm_y_kernel(
    const float* __restrict__ x,
    const float* __restrict__ W,
    unsigned* __restrict__ y,   // [N][64] packed words
    int n) {
  __shared__ float wt[D][LDP];
  __shared__ float zs[GP][LDP];

  int t = threadIdx.x;
  int node0 = blockIdx.x * GNODES;

  #pragma unroll
  for (int it = 0; it < 16; ++it) {
    int f = t + it * 256;
    int j = f >> 5;
    int k4 = f & 31;
    *(float4*)&wt[j][k4 * 4] = ((const float4*)W)[f];
  }

  int tj = t & 31;
  int ns = t >> 5;
  int j0 = tj * 2;  // dims j0, j0+1, j0+64, j0+65

  for (int p = 0; p < 4; ++p) {
    int nb = node0 + p * GP;
    __syncthreads();
    #pragma unroll
    for (int it = 0; it < 2; ++it) {
      int f = t + it * 256;
      int r = f >> 5;
      int c4 = f & 31;
      int node = nb + r;
      float4 v = make_float4(0.f, 0.f, 0.f, 0.f);
      if (node < n) v = ((const float4*)(x + (size_t)node * D))[c4];
      *(float4*)&zs[r][c4 * 4] = v;
    }
    __syncthreads();

    float acc[2][4] = {};
    #pragma unroll 4
    for (int k = 0; k < D; k += 4) {
      float4 w0 = *(const float4*)&wt[j0][k];
      float4 w1 = *(const float4*)&wt[j0 + 1][k];
      float4 w2 = *(const float4*)&wt[j0 + 64][k];
      float4 w3 = *(const float4*)&wt[j0 + 65][k];
      float4 z0 = *(const float4*)&zs[ns * 2 + 0][k];
      float4 z1 = *(const float4*)&zs[ns * 2 + 1][k];
      acc[0][0] += z0.x * w0.x + z0.y * w0.y + z0.z * w0.z + z0.w * w0.w;
      acc[0][1] += z0.x * w1.x + z0.y * w1.y + z0.z * w1.z + z0.w * w1.w;
      acc[0][2] += z0.x * w2.x + z0.y * w2.y + z0.z * w2.z + z0.w * w2.w;
      acc[0][3] += z0.x * w3.x + z0.y * w3.y + z0.z * w3.z + z0.w * w3.w;
      acc[1][0] += z1.x * w0.x + z1.y * w0.y + z1.z * w0.z + z1.w * w0.w;
      acc[1][1] += z1.x * w1.x + z1.y * w1.y + z1.z * w1.z + z1.w * w1.w;
      acc[1][2] += z1.x * w2.x + z1.y * w2.y + z1.z * w2.z + z1.w * w2.w;
      acc[1][3] += z1.x * w3.x + z1.y * w3.y + z1.z * w3.z + z1.w * w3.w;
    }

    #pragma unroll
    for (int ii = 0; ii < 2; ++ii) {
      int node = nb + ns * 2 + ii;
      if (node < n) {
        uint2 o;
        o.x = (unsigned)f2bf(acc[ii][0]) | ((unsigned)f2bf(acc[ii][2]) << 16);
        o.y = (unsigned)f2bf(acc[ii][1]) | ((unsigned)f2bf(acc[ii][3]) << 16);
        *(uint2*)&y[(size_t)node * 64 + j0] = o;
      }
    }
  }
}

// ---------------------------------------------------------------------------
// Kernel 4: gather — wave per row, register accumulation, no atomics.
// Iterates the row's 8 XCD cells; 4-deep unrolled independent y loads;
// fused bias + ReLU; out written once.
// ---------------------------------------------------------------------------
__global__ __launch_bounds__(256) void gather_kernel(
    const int* __restrict__ rcursor,     // [N][8]
    const unsigned* __restrict__ pairs,  // [N][8][SCAP]
    const unsigned* __restrict__ y,      // [N][64] packed (d, d+64)
    const float* __restrict__ bias,
    float* __restrict__ out) {
  int row = (int)((blockIdx.x * blockDim.x + threadIdx.x) >> 6);
  int lane = threadIdx.x & 63;
  if (row >= N_NODES_C) return;
  const unsigned* pp = pairs + ((size_t)row << 8);
  const int* cc = rcursor + (row << 3);
  float aL = 0.f, aH = 0.f;
  #pragma unroll
  for (int s = 0; s < NSHARD; ++s) {
    int deg = cc[s];
    if (deg > SCAP) deg = SCAP;
    const unsigned* cp = pp + (s << 5);
    int p = 0;
    for (; p + 3 < deg; p += 4) {
      unsigned e0 = cp[p + 0];
      unsigned e1 = cp[p + 1];
      unsigned e2 = cp[p + 2];
      unsigned e3 = cp[p + 3];
      unsigned u0 = y[(size_t)(e0 & 0xffffu) * 64 + lane];
      unsigned u1 = y[(size_t)(e1 & 0xffffu) * 64 + lane];
      unsigned u2 = y[(size_t)(e2 & 0xffffu) * 64 + lane];
      unsigned u3 = y[(size_t)(e3 & 0xffffu) * 64 + lane];
      float v0 = bf_hi(e0);
      float v1 = bf_hi(e1);
      float v2 = bf_hi(e2);
      float v3 = bf_hi(e3);
      aL += v0 * bf_lo(u0) + v1 * bf_lo(u1) + v2 * bf_lo(u2) + v3 * bf_lo(u3);
      aH += v0 * bf_hi(u0) + v1 * bf_hi(u1) + v2 * bf_hi(u2) + v3 * bf_hi(u3);
    }
    for (; p < deg; ++p) {
      unsigned e0 = cp[p];
      unsigned u0 = y[(size_t)(e0 & 0xffffu) * 64 + lane];
      float v0 = bf_hi(e0);
      aL += v0 * bf_lo(u0);
      aH += v0 * bf_hi(u0);
    }
  }
  out[(size_t)row * D + lane] = fmaxf(aL + bias[lane], 0.0f);
  out[(size_t)row * D + lane + 64] = fmaxf(aH + bias[lane + 64], 0.0f);
}

extern "C" void kernel_launch(void* const* d_in, const int* in_sizes, int n_in,
                              void* d_out, int out_size, void* d_ws, size_t ws_size,
                              hipStream_t stream) {
  const float* x = (const float*)d_in[0];
  const int* lp_rows = (const int*)d_in[1];
  const int* lp_cols = (const int*)d_in[2];
  const float* lp_vals = (const float*)d_in[3];
  const int* hp_rows = (const int*)d_in[4];
  const int* hp_cols = (const int*)d_in[5];
  const float* hp_vals = (const float*)d_in[6];
  const float* alpha_w = (const float*)d_in[7];
  const float* alpha_b = (const float*)d_in[8];
  const float* W = (const float*)d_in[9];
  const float* bias = (const float*)d_in[10];

  float* out = (float*)d_out;                      // [N, 128]
  float* alpha_out = out + (size_t)N_NODES_C * D;  // [N, 1] output tail

  char* ws = (char*)d_ws;
  unsigned* y = (unsigned*)ws;           ws += (size_t)N_NODES_C * 64 * 4;  // 12.8 MB
  float* alpha_ws = (float*)ws;          ws += 200192;
  int* rcursor = (int*)ws;               ws += (size_t)N_NODES_C * NSHARD * 4;  // 1.6 MB
  unsigned* pairs = (unsigned*)ws;
  ws += (size_t)N_NODES_C * NSHARD * SCAP * 4;     // 51.2 MB

  hipMemsetAsync(rcursor, 0, (size_t)N_NODES_C * NSHARD * sizeof(int), stream);

  alpha_kernel<<<(N_NODES_C + 3) / 4, 256, 0, stream>>>(
      x, alpha_w, alpha_b, alpha_out, alpha_ws, N_NODES_C);

  fill_kernel<<<(N_EDGES2_C + 255) / 256, 256, 0, stream>>>(
      lp_rows, lp_cols, lp_vals, hp_rows, hp_cols, hp_vals,
      alpha_ws, rcursor, pairs);

  gemm_y_kernel<<<(N_NODES_C + GNODES - 1) / GNODES, 256, 0, stream>>>(
      x, W, y, N_NODES_C);

  gather_kernel<<<(N_NODES_C * 64 + 255) / 256, 256, 0, stream>>>(
      rcursor, pairs, (const unsigned*)y, bias, out);
}

// Round 11
// 333.757 us; speedup vs baseline: 1.0299x; 1.0299x over previous
//
#include <hip/hip_runtime.h>

#define N_NODES_C 50000
#define N_EDGES_C 800000
#define N_EDGES2_C (2 * N_EDGES_C)
#define D 128
#define NSHARD 8
#define SCAP 16    // slots per (row,xcd) cell = one 64 B line
#define OFCAP 4096 // overflow list capacity (expected use ~0)

static __device__ __forceinline__ unsigned short f2bf(float f) {
  unsigned u = __float_as_uint(f);
  u += 0x7fff + ((u >> 16) & 1);  // round-to-nearest-even
  return (unsigned short)(u >> 16);
}
static __device__ __forceinline__ float bf_lo(unsigned u) {
  return __uint_as_float(u << 16);
}
static __device__ __forceinline__ float bf_hi(unsigned u) {
  return __uint_as_float(u & 0xffff0000u);
}

// Physical XCD id (0..7), wave-uniform; steers L2 locality only.
static __device__ __forceinline__ int xcd_id() {
  int v;
  asm volatile("s_getreg_b32 %0, hwreg(HW_REG_XCC_ID, 0, 4)" : "=s"(v));
  return v & (NSHARD - 1);
}

// ---------------------------------------------------------------------------
// Kernel 1: fill — XCD-sharded scatter. Cell (row,xcd) = 16 slots = one
// 64 B line; cell + its cursor written by exactly one XCD (no cross-XCD
// line ping-pong). Slot: col:16 | bf16(gate-scaled val):16. Cell overflow
// (P ~ 2e-7 per cell) goes exactly to a global overflow list.
// ---------------------------------------------------------------------------
__global__ __launch_bounds__(256) void fill_kernel(
    const int* __restrict__ lp_rows, const int* __restrict__ lp_cols,
    const float* __restrict__ lp_vals,
    const int* __restrict__ hp_rows, const int* __restrict__ hp_cols,
    const float* __restrict__ hp_vals,
    const float* __restrict__ alpha,
    int* __restrict__ rcursor,      // [N][8], zeroed before launch
    unsigned* __restrict__ pairs,   // [N][8][SCAP]
    int* __restrict__ ofcnt,        // zeroed
    uint2* __restrict__ ofl) {
  int e = blockIdx.x * 256 + threadIdx.x;
  if (e >= N_EDGES2_C) return;
  int xcc = xcd_id();
  int r, c;
  float v;
  if (e < N_EDGES_C) {
    r = lp_rows[e];
    c = lp_cols[e];
    v = lp_vals[e] * alpha[r];
  } else {
    int i = e - N_EDGES_C;
    r = hp_rows[i];
    c = hp_cols[i];
    v = hp_vals[i] * (1.0f - alpha[r]);
  }
  int p = atomicAdd(&rcursor[(r << 3) + xcc], 1);
  if (p < SCAP) {
    unsigned pk = (unsigned)c | ((unsigned)f2bf(v) << 16);
    pairs[((size_t)r << 7) + (xcc << 4) + p] = pk;
  } else {
    int q = atomicAdd(ofcnt, 1);
    if (q < OFCAP)
      ofl[q] = make_uint2(((unsigned)r << 16) | (unsigned)c,
                          (unsigned)__float_as_int(v));
  }
}

// ---------------------------------------------------------------------------
// Kernel 2: gemm_y + fused alpha. y = x @ W^T (bf16, paired packing: word d
// = (dim d, dim d+64)); alpha computed by wave 0 from the LDS-staged x rows
// (zs) each pass: alpha = sigmoid(dot(x_row, aw) + ab).
// ---------------------------------------------------------------------------
#define GNODES 64
#define GP 16
#define LDP 132

__global__ __launch_bounds__(256) void gemm_y_kernel(
    const float* __restrict__ x,
    const float* __restrict__ W,
    const float* __restrict__ aw,
    const float* __restrict__ ab,
    unsigned* __restrict__ y,        // [N][64] packed words
    float* __restrict__ alpha_out,
    float* __restrict__ alpha_ws,
    int n) {
  __shared__ float wt[D][LDP];
  __shared__ float zs[GP][LDP];

  int t = threadIdx.x;
  int lane = t & 63;
  int node0 = blockIdx.x * GNODES;

  float awv0 = aw[lane];        // used by wave 0 for alpha
  float awv1 = aw[lane + 64];
  float ab0 = ab[0];

  #pragma unroll
  for (int it = 0; it < 16; ++it) {
    int f = t + it * 256;
    int j = f >> 5;
    int k4 = f & 31;
    *(float4*)&wt[j][k4 * 4] = ((const float4*)W)[f];
  }

  int tj = t & 31;
  int ns = t >> 5;
  int j0 = tj * 2;  // dims j0, j0+1, j0+64, j0+65

  for (int p = 0; p < 4; ++p) {
    int nb = node0 + p * GP;
    __syncthreads();
    #pragma unroll
    for (int it = 0; it < 2; ++it) {
      int f = t + it * 256;
      int r = f >> 5;
      int c4 = f & 31;
      int node = nb + r;
      float4 v = make_float4(0.f, 0.f, 0.f, 0.f);
      if (node < n) v = ((const float4*)(x + (size_t)node * D))[c4];
      *(float4*)&zs[r][c4 * 4] = v;
    }
    __syncthreads();

    // wave 0: alpha for this pass's 16 nodes (zs is stable until next sync)
    if (t < 64) {
      for (int r = 0; r < GP; ++r) {
        float s = zs[r][lane] * awv0 + zs[r][lane + 64] * awv1;
        #pragma unroll
        for (int off = 32; off > 0; off >>= 1)
          s += __shfl_down(s, off);
        int node = nb + r;
        if (lane == 0 && node < n) {
          float a = 1.0f / (1.0f + __expf(-(s + ab0)));
          alpha_out[node] = a;
          alpha_ws[node] = a;
        }
      }
    }

    float acc[2][4] = {};
    #pragma unroll 4
    for (int k = 0; k < D; k += 4) {
      float4 w0 = *(const float4*)&wt[j0][k];
      float4 w1 = *(const float4*)&wt[j0 + 1][k];
      float4 w2 = *(const float4*)&wt[j0 + 64][k];
      float4 w3 = *(const float4*)&wt[j0 + 65][k];
      float4 z0 = *(const float4*)&zs[ns * 2 + 0][k];
      float4 z1 = *(const float4*)&zs[ns * 2 + 1][k];
      acc[0][0] += z0.x * w0.x + z0.y * w0.y + z0.z * w0.z + z0.w * w0.w;
      acc[0][1] += z0.x * w1.x + z0.y * w1.y + z0.z * w1.z + z0.w * w1.w;
      acc[0][2] += z0.x * w2.x + z0.y * w2.y + z0.z * w2.z + z0.w * w2.w;
      acc[0][3] += z0.x * w3.x + z0.y * w3.y + z0.z * w3.z + z0.w * w3.w;
      acc[1][0] += z1.x * w0.x + z1.y * w0.y + z1.z * w0.z + z1.w * w0.w;
      acc[1][1] += z1.x * w1.x + z1.y * w1.y + z1.z * w1.z + z1.w * w1.w;
      acc[1][2] += z1.x * w2.x + z1.y * w2.y + z1.z * w2.z + z1.w * w2.w;
      acc[1][3] += z1.x * w3.x + z1.y * w3.y + z1.z * w3.z + z1.w * w3.w;
    }

    #pragma unroll
    for (int ii = 0; ii < 2; ++ii) {
      int node = nb + ns * 2 + ii;
      if (node < n) {
        uint2 o;
        o.x = (unsigned)f2bf(acc[ii][0]) | ((unsigned)f2bf(acc[ii][2]) << 16);
        o.y = (unsigned)f2bf(acc[ii][1]) | ((unsigned)f2bf(acc[ii][3]) << 16);
        *(uint2*)&y[(size_t)node * 64 + j0] = o;
      }
    }
  }
}

// ---------------------------------------------------------------------------
// Kernel 3: gather — wave per row, register accumulation, no atomics.
// The row's 8 cells (512 B contiguous) are ingested with TWO coalesced
// 64-lane loads into registers; each edge is then broadcast via __shfl
// (wave-uniform index -> readlane). 2-deep unrolled y loads. Overflow list
// scanned at the end (expected empty). Fused bias + ReLU.
// ---------------------------------------------------------------------------
__global__ __launch_bounds__(256) void gather_kernel(
    const int* __restrict__ rcursor,     // [N][8]
    const unsigned* __restrict__ pairs,  // [N][8][SCAP]
    const unsigned* __restrict__ y,      // [N][64] packed (d, d+64)
    const float* __restrict__ bias,
    const int* __restrict__ ofcnt,
    const uint2* __restrict__ ofl,
    float* __restrict__ out) {
  int row = (int)((blockIdx.x * blockDim.x + threadIdx.x) >> 6);
  int lane = threadIdx.x & 63;
  if (row >= N_NODES_C) return;

  const unsigned* rp = pairs + ((size_t)row << 7);
  unsigned w0 = rp[lane];        // slots 0..63   (cells 0..3)
  unsigned w1 = rp[64 + lane];   // slots 64..127 (cells 4..7)
  const int* cc = rcursor + (row << 3);

  float aL = 0.f, aH = 0.f;
  #pragma unroll
  for (int s = 0; s < NSHARD; ++s) {
    int ds = cc[s];
    if (ds > SCAP) ds = SCAP;
    unsigned wsrc = (s < 4) ? w0 : w1;
    int base = (s & 3) << 4;
    int p = 0;
    for (; p + 1 < ds; p += 2) {
      unsigned pk0 = (unsigned)__shfl((int)wsrc, base + p);
      unsigned pk1 = (unsigned)__shfl((int)wsrc, base + p + 1);
      unsigned u0 = y[(size_t)(pk0 & 0xffffu) * 64 + lane];
      unsigned u1 = y[(size_t)(pk1 & 0xffffu) * 64 + lane];
      float v0 = bf_hi(pk0);
      float v1 = bf_hi(pk1);
      aL += v0 * bf_lo(u0) + v1 * bf_lo(u1);
      aH += v0 * bf_hi(u0) + v1 * bf_hi(u1);
    }
    if (p < ds) {
      unsigned pk = (unsigned)__shfl((int)wsrc, base + p);
      unsigned u = y[(size_t)(pk & 0xffffu) * 64 + lane];
      aL += bf_hi(pk) * bf_lo(u);
      aH += bf_hi(pk) * bf_hi(u);
    }
  }

  // overflow entries (expected 0)
  int nof = *ofcnt;
  if (nof > OFCAP) nof = OFCAP;
  for (int i = 0; i < nof; ++i) {
    uint2 o = ofl[i];
    if ((int)(o.x >> 16) == row) {
      unsigned u = y[(size_t)(o.x & 0xffffu) * 64 + lane];
      float v = __int_as_float((int)o.y);
      aL += v * bf_lo(u);
      aH += v * bf_hi(u);
    }
  }

  out[(size_t)row * D + lane] = fmaxf(aL + bias[lane], 0.0f);
  out[(size_t)row * D + lane + 64] = fmaxf(aH + bias[lane + 64], 0.0f);
}

extern "C" void kernel_launch(void* const* d_in, const int* in_sizes, int n_in,
                              void* d_out, int out_size, void* d_ws, size_t ws_size,
                              hipStream_t stream) {
  const float* x = (const float*)d_in[0];
  const int* lp_rows = (const int*)d_in[1];
  const int* lp_cols = (const int*)d_in[2];
  const float* lp_vals = (const float*)d_in[3];
  const int* hp_rows = (const int*)d_in[4];
  const int* hp_cols = (const int*)d_in[5];
  const float* hp_vals = (const float*)d_in[6];
  const float* alpha_w = (const float*)d_in[7];
  const float* alpha_b = (const float*)d_in[8];
  const float* W = (const float*)d_in[9];
  const float* bias = (const float*)d_in[10];

  float* out = (float*)d_out;                      // [N, 128]
  float* alpha_out = out + (size_t)N_NODES_C * D;  // [N, 1] output tail

  char* ws = (char*)d_ws;
  unsigned* y = (unsigned*)ws;   ws += (size_t)N_NODES_C * 64 * 4;          // 12.8 MB
  float* alpha_ws = (float*)ws;  ws += 200192;
  int* rcursor = (int*)ws;       ws += (size_t)N_NODES_C * NSHARD * 4;      // 1.6 MB
  int* ofcnt = (int*)ws;         ws += 256;
  uint2* ofl = (uint2*)ws;       ws += (size_t)OFCAP * 8;                   // 32 KB
  unsigned* pairs = (unsigned*)ws;
  ws += (size_t)N_NODES_C * NSHARD * SCAP * 4;                              // 25.6 MB

  // zero cursors + overflow counter in one memset (contiguous)
  hipMemsetAsync(rcursor, 0,
                 (size_t)N_NODES_C * NSHARD * sizeof(int) + 256, stream);

  gemm_y_kernel<<<(N_NODES_C + GNODES - 1) / GNODES, 256, 0, stream>>>(
      x, W, alpha_w, alpha_b, y, alpha_out, alpha_ws, N_NODES_C);

  fill_kernel<<<(N_EDGES2_C + 255) / 256, 256, 0, stream>>>(
      lp_rows, lp_cols, lp_vals, hp_rows, hp_cols, hp_vals,
      alpha_ws, rcursor, pairs, ofcnt, ofl);

  gather_kernel<<<(N_NODES_C * 64 + 255) / 256, 256, 0, stream>>>(
      rcursor, pairs, (const unsigned*)y, bias, ofcnt, ofl, out);
}

// Round 12
// 331.865 us; speedup vs baseline: 1.0357x; 1.0057x over previous
//
#include <hip/hip_runtime.h>

#define N_NODES_C 50000
#define N_EDGES_C 800000
#define N_EDGES2_C (2 * N_EDGES_C)
#define D 128
#define NSHARD 8
#define SCAP 16    // slots per (row,xcd) cell = one 64 B line
#define OFCAP 4096 // overflow list capacity (expected use ~0)

static __device__ __forceinline__ unsigned short f2bf(float f) {
  unsigned u = __float_as_uint(f);
  u += 0x7fff + ((u >> 16) & 1);  // round-to-nearest-even
  return (unsigned short)(u >> 16);
}
static __device__ __forceinline__ float bf_lo(unsigned u) {
  return __uint_as_float(u << 16);
}
static __device__ __forceinline__ float bf_hi(unsigned u) {
  return __uint_as_float(u & 0xffff0000u);
}

// Physical XCD id (0..7), wave-uniform; steers L2 locality only.
static __device__ __forceinline__ int xcd_id() {
  int v;
  asm volatile("s_getreg_b32 %0, hwreg(HW_REG_XCC_ID, 0, 4)" : "=s"(v));
  return v & (NSHARD - 1);
}

// ---------------------------------------------------------------------------
// Kernel 1: fill — XCD-sharded scatter. pairs cell (row,xcd) = one 64 B
// line; rcursor TRANSPOSED [xcd][N] so cursor lines are also single-XCD
// (R11's [N][8] layout ping-ponged cursor lines across all 8 XCDs).
// Slot: col:16 | bf16(gate-scaled val):16. Overflow -> exact global list.
// ---------------------------------------------------------------------------
__global__ __launch_bounds__(256) void fill_kernel(
    const int* __restrict__ lp_rows, const int* __restrict__ lp_cols,
    const float* __restrict__ lp_vals,
    const int* __restrict__ hp_rows, const int* __restrict__ hp_cols,
    const float* __restrict__ hp_vals,
    const float* __restrict__ alpha,
    int* __restrict__ rcursor,      // [NSHARD][N], zeroed before launch
    unsigned* __restrict__ pairs,   // [N][NSHARD][SCAP]
    int* __restrict__ ofcnt,        // zeroed
    uint2* __restrict__ ofl) {
  int e = blockIdx.x * 256 + threadIdx.x;
  if (e >= N_EDGES2_C) return;
  int xcc = xcd_id();
  int r, c;
  float v;
  if (e < N_EDGES_C) {
    r = lp_rows[e];
    c = lp_cols[e];
    v = lp_vals[e] * alpha[r];
  } else {
    int i = e - N_EDGES_C;
    r = hp_rows[i];
    c = hp_cols[i];
    v = hp_vals[i] * (1.0f - alpha[r]);
  }
  int p = atomicAdd(&rcursor[xcc * N_NODES_C + r], 1);
  if (p < SCAP) {
    unsigned pk = (unsigned)c | ((unsigned)f2bf(v) << 16);
    pairs[((size_t)r << 7) + (xcc << 4) + p] = pk;
  } else {
    int q = atomicAdd(ofcnt, 1);
    if (q < OFCAP)
      ofl[q] = make_uint2(((unsigned)r << 16) | (unsigned)c,
                          (unsigned)__float_as_int(v));
  }
}

// ---------------------------------------------------------------------------
// Kernel 2: gemm_y + fused alpha. y = x @ W^T (bf16 paired packing: word d
// = (dim d, dim d+64)). LANE REMAP: tj = t>>3, ns = t&7 -> per wave only 8
// distinct wt rows (8-lane same-address broadcast, free) and 8 distinct zs
// rows; residual aliasing is 2-way (free). R11's tj=t&31 gave 8-way wt
// conflicts (6.4M SQ_LDS_BANK_CONFLICT).
// ---------------------------------------------------------------------------
#define GNODES 64
#define GP 16
#define LDP 132

__global__ __launch_bounds__(256) void gemm_y_kernel(
    const float* __restrict__ x,
    const float* __restrict__ W,
    const float* __restrict__ aw,
    const float* __restrict__ ab,
    unsigned* __restrict__ y,        // [N][64] packed words
    float* __restrict__ alpha_out,
    float* __restrict__ alpha_ws,
    int n) {
  __shared__ float wt[D][LDP];
  __shared__ float zs[GP][LDP];

  int t = threadIdx.x;
  int lane = t & 63;
  int node0 = blockIdx.x * GNODES;

  float awv0 = aw[lane];        // used by wave 0 for alpha
  float awv1 = aw[lane + 64];
  float ab0 = ab[0];

  #pragma unroll
  for (int it = 0; it < 16; ++it) {
    int f = t + it * 256;
    int j = f >> 5;
    int k4 = f & 31;
    *(float4*)&wt[j][k4 * 4] = ((const float4*)W)[f];
  }

  int tj = t >> 3;   // 0..31: j-pair index (wave-sharded: 8 per wave)
  int ns = t & 7;    // 0..7: node-pair within pass
  int j0 = tj * 2;   // dims j0, j0+1, j0+64, j0+65

  for (int p = 0; p < 4; ++p) {
    int nb = node0 + p * GP;
    __syncthreads();
    #pragma unroll
    for (int it = 0; it < 2; ++it) {
      int f = t + it * 256;
      int r = f >> 5;
      int c4 = f & 31;
      int node = nb + r;
      float4 v = make_float4(0.f, 0.f, 0.f, 0.f);
      if (node < n) v = ((const float4*)(x + (size_t)node * D))[c4];
      *(float4*)&zs[r][c4 * 4] = v;
    }
    __syncthreads();

    // wave 0: alpha for this pass's 16 nodes (zs stable until next sync)
    if (t < 64) {
      for (int r = 0; r < GP; ++r) {
        float s = zs[r][lane] * awv0 + zs[r][lane + 64] * awv1;
        #pragma unroll
        for (int off = 32; off > 0; off >>= 1)
          s += __shfl_down(s, off);
        int node = nb + r;
        if (lane == 0 && node < n) {
          float a = 1.0f / (1.0f + __expf(-(s + ab0)));
          alpha_out[node] = a;
          alpha_ws[node] = a;
        }
      }
    }

    float acc[2][4] = {};
    #pragma unroll 4
    for (int k = 0; k < D; k += 4) {
      float4 w0 = *(const float4*)&wt[j0][k];
      float4 w1 = *(const float4*)&wt[j0 + 1][k];
      float4 w2 = *(const float4*)&wt[j0 + 64][k];
      float4 w3 = *(const float4*)&wt[j0 + 65][k];
      float4 z0 = *(const float4*)&zs[ns * 2 + 0][k];
      float4 z1 = *(const float4*)&zs[ns * 2 + 1][k];
      acc[0][0] += z0.x * w0.x + z0.y * w0.y + z0.z * w0.z + z0.w * w0.w;
      acc[0][1] += z0.x * w1.x + z0.y * w1.y + z0.z * w1.z + z0.w * w1.w;
      acc[0][2] += z0.x * w2.x + z0.y * w2.y + z0.z * w2.z + z0.w * w2.w;
      acc[0][3] += z0.x * w3.x + z0.y * w3.y + z0.z * w3.z + z0.w * w3.w;
      acc[1][0] += z1.x * w0.x + z1.y * w0.y + z1.z * w0.z + z1.w * w0.w;
      acc[1][1] += z1.x * w1.x + z1.y * w1.y + z1.z * w1.z + z1.w * w1.w;
      acc[1][2] += z1.x * w2.x + z1.y * w2.y + z1.z * w2.z + z1.w * w2.w;
      acc[1][3] += z1.x * w3.x + z1.y * w3.y + z1.z * w3.z + z1.w * w3.w;
    }

    #pragma unroll
    for (int ii = 0; ii < 2; ++ii) {
      int node = nb + ns * 2 + ii;
      if (node < n) {
        uint2 o;
        o.x = (unsigned)f2bf(acc[ii][0]) | ((unsigned)f2bf(acc[ii][2]) << 16);
        o.y = (unsigned)f2bf(acc[ii][1]) | ((unsigned)f2bf(acc[ii][3]) << 16);
        *(uint2*)&y[(size_t)node * 64 + j0] = o;
      }
    }
  }
}

// ---------------------------------------------------------------------------
// Kernel 3: gather — wave per row, register accumulation, no atomics.
// Row's 8 cells (512 B contiguous) ingested with two coalesced 64-lane
// loads; edges broadcast via __shfl (readlane). Cursors read from the
// transposed [xcd][N] layout. Fused bias + ReLU.
// ---------------------------------------------------------------------------
__global__ __launch_bounds__(256) void gather_kernel(
    const int* __restrict__ rcursor,     // [NSHARD][N]
    const unsigned* __restrict__ pairs,  // [N][NSHARD][SCAP]
    const unsigned* __restrict__ y,      // [N][64] packed (d, d+64)
    const float* __restrict__ bias,
    const int* __restrict__ ofcnt,
    const uint2* __restrict__ ofl,
    float* __restrict__ out) {
  int row = (int)((blockIdx.x * blockDim.x + threadIdx.x) >> 6);
  int lane = threadIdx.x & 63;
  if (row >= N_NODES_C) return;

  const unsigned* rp = pairs + ((size_t)row << 7);
  unsigned w0 = rp[lane];        // slots 0..63   (cells 0..3)
  unsigned w1 = rp[64 + lane];   // slots 64..127 (cells 4..7)

  float aL = 0.f, aH = 0.f;
  #pragma unroll
  for (int s = 0; s < NSHARD; ++s) {
    int ds = rcursor[(size_t)s * N_NODES_C + row];
    if (ds > SCAP) ds = SCAP;
    unsigned wsrc = (s < 4) ? w0 : w1;
    int base = (s & 3) << 4;
    int p = 0;
    for (; p + 1 < ds; p += 2) {
      unsigned pk0 = (unsigned)__shfl((int)wsrc, base + p);
      unsigned pk1 = (unsigned)__shfl((int)wsrc, base + p + 1);
      unsigned u0 = y[(size_t)(pk0 & 0xffffu) * 64 + lane];
      unsigned u1 = y[(size_t)(pk1 & 0xffffu) * 64 + lane];
      float v0 = bf_hi(pk0);
      float v1 = bf_hi(pk1);
      aL += v0 * bf_lo(u0) + v1 * bf_lo(u1);
      aH += v0 * bf_hi(u0) + v1 * bf_hi(u1);
    }
    if (p < ds) {
      unsigned pk = (unsigned)__shfl((int)wsrc, base + p);
      unsigned u = y[(size_t)(pk & 0xffffu) * 64 + lane];
      aL += bf_hi(pk) * bf_lo(u);
      aH += bf_hi(pk) * bf_hi(u);
    }
  }

  // overflow entries (expected 0)
  int nof = *ofcnt;
  if (nof > OFCAP) nof = OFCAP;
  for (int i = 0; i < nof; ++i) {
    uint2 o = ofl[i];
    if ((int)(o.x >> 16) == row) {
      unsigned u = y[(size_t)(o.x & 0xffffu) * 64 + lane];
      float v = __int_as_float((int)o.y);
      aL += v * bf_lo(u);
      aH += v * bf_hi(u);
    }
  }

  out[(size_t)row * D + lane] = fmaxf(aL + bias[lane], 0.0f);
  out[(size_t)row * D + lane + 64] = fmaxf(aH + bias[lane + 64], 0.0f);
}

extern "C" void kernel_launch(void* const* d_in, const int* in_sizes, int n_in,
                              void* d_out, int out_size, void* d_ws, size_t ws_size,
                              hipStream_t stream) {
  const float* x = (const float*)d_in[0];
  const int* lp_rows = (const int*)d_in[1];
  const int* lp_cols = (const int*)d_in[2];
  const float* lp_vals = (const float*)d_in[3];
  const int* hp_rows = (const int*)d_in[4];
  const int* hp_cols = (const int*)d_in[5];
  const float* hp_vals = (const float*)d_in[6];
  const float* alpha_w = (const float*)d_in[7];
  const float* alpha_b = (const float*)d_in[8];
  const float* W = (const float*)d_in[9];
  const float* bias = (const float*)d_in[10];

  float* out = (float*)d_out;                      // [N, 128]
  float* alpha_out = out + (size_t)N_NODES_C * D;  // [N, 1] output tail

  char* ws = (char*)d_ws;
  unsigned* y = (unsigned*)ws;   ws += (size_t)N_NODES_C * 64 * 4;          // 12.8 MB
  float* alpha_ws = (float*)ws;  ws += 200192;
  int* rcursor = (int*)ws;       ws += (size_t)N_NODES_C * NSHARD * 4;      // 1.6 MB
  int* ofcnt = (int*)ws;         ws += 256;
  uint2* ofl = (uint2*)ws;       ws += (size_t)OFCAP * 8;                   // 32 KB
  unsigned* pairs = (unsigned*)ws;
  ws += (size_t)N_NODES_C * NSHARD * SCAP * 4;                              // 25.6 MB

  // zero cursors + overflow counter in one memset (contiguous)
  hipMemsetAsync(rcursor, 0,
                 (size_t)N_NODES_C * NSHARD * sizeof(int) + 256, stream);

  gemm_y_kernel<<<(N_NODES_C + GNODES - 1) / GNODES, 256, 0, stream>>>(
      x, W, alpha_w, alpha_b, y, alpha_out, alpha_ws, N_NODES_C);

  fill_kernel<<<(N_EDGES2_C + 255) / 256, 256, 0, stream>>>(
      lp_rows, lp_cols, lp_vals, hp_rows, hp_cols, hp_vals,
      alpha_ws, rcursor, pairs, ofcnt, ofl);

  gather_kernel<<<(N_NODES_C * 64 + 255) / 256, 256, 0, stream>>>(
      rcursor, pairs, (const unsigned*)y, bias, ofcnt, ofl, out);
}

// Round 13
// 306.291 us; speedup vs baseline: 1.1222x; 1.0835x over previous
//
#include <hip/hip_runtime.h>

#define N_NODES_C 50000
#define N_EDGES_C 800000
#define N_EDGES2_C (2 * N_EDGES_C)
#define D 128
#define NSHARD 8
#define SCAP 16    // slots per (row,xcd) cell = one 64 B line
#define OFCAP 4096 // overflow list capacity (expected use ~0)

#define GNODES 64
#define GP 16
#define LDP 132
#define GRID ((N_NODES_C + GNODES - 1) / GNODES)          // 782
#define EPB ((N_EDGES2_C + GRID - 1) / GRID)              // 2047

static __device__ __forceinline__ unsigned short f2bf(float f) {
  unsigned u = __float_as_uint(f);
  u += 0x7fff + ((u >> 16) & 1);  // round-to-nearest-even
  return (unsigned short)(u >> 16);
}
static __device__ __forceinline__ float bf_lo(unsigned u) {
  return __uint_as_float(u << 16);
}
static __device__ __forceinline__ float bf_hi(unsigned u) {
  return __uint_as_float(u & 0xffff0000u);
}

// Physical XCD id (0..7), wave-uniform; steers L2 locality only.
static __device__ __forceinline__ int xcd_id() {
  int v;
  asm volatile("s_getreg_b32 %0, hwreg(HW_REG_XCC_ID, 0, 4)" : "=s"(v));
  return v & (NSHARD - 1);
}

// ---------------------------------------------------------------------------
// Kernel 1: alpha[i] = sigmoid(dot(x[i], alpha_w) + alpha_b), wave per node.
// (Separate again: the fused kernel's fill phase needs alpha at launch.)
// ---------------------------------------------------------------------------
__global__ __launch_bounds__(256) void alpha_kernel(
    const float* __restrict__ x,
    const float* __restrict__ aw,
    const float* __restrict__ ab,
    float* __restrict__ alpha_out,
    float* __restrict__ alpha_ws,
    int n) {
  int wave = (int)((blockIdx.x * blockDim.x + threadIdx.x) >> 6);
  int lane = threadIdx.x & 63;
  if (wave >= n) return;
  const float* xr = x + (size_t)wave * D;
  float s = xr[lane] * aw[lane] + xr[lane + 64] * aw[lane + 64];
  #pragma unroll
  for (int off = 32; off > 0; off >>= 1)
    s += __shfl_down(s, off);
  if (lane == 0) {
    float a = 1.0f / (1.0f + __expf(-(s + ab[0])));
    alpha_out[wave] = a;
    alpha_ws[wave] = a;
  }
}

// ---------------------------------------------------------------------------
// Kernel 2 (FUSED): phase A = gemm_y tile (VALU/LDS-bound), phase B = fill
// edge chunk (latency/atomic-bound). Independent work in one launch so the
// CU scheduler overlaps the two regimes across blocks (time ~ max, not sum).
//
// Phase A: y = x @ W^T, bf16 paired packing (word d = dims (d, d+64)).
// Lane map tj=t>>3, ns=t&7: wt rows 8-lane-broadcast, zs 2-way -> conflict-
// free (R12-verified: 6.4M -> 0 SQ_LDS_BANK_CONFLICT).
// Phase B: XCD-sharded scatter, cell (row,xcd) = one 64 B line; cursors
// transposed [xcd][N]. Slot: col:16 | bf16(gate-scaled val):16.
// ---------------------------------------------------------------------------
__global__ __launch_bounds__(256) void gemm_fill_kernel(
    const float* __restrict__ x,
    const float* __restrict__ W,
    unsigned* __restrict__ y,        // [N][64] packed words
    const int* __restrict__ lp_rows, const int* __restrict__ lp_cols,
    const float* __restrict__ lp_vals,
    const int* __restrict__ hp_rows, const int* __restrict__ hp_cols,
    const float* __restrict__ hp_vals,
    const float* __restrict__ alpha,
    int* __restrict__ rcursor,       // [NSHARD][N], zeroed before launch
    unsigned* __restrict__ pairs,    // [N][NSHARD][SCAP]
    int* __restrict__ ofcnt,
    uint2* __restrict__ ofl,
    int n) {
  __shared__ float wt[D][LDP];
  __shared__ float zs[GP][LDP];

  int t = threadIdx.x;
  int node0 = blockIdx.x * GNODES;

  // ---------------- Phase A: gemm tile ----------------
  #pragma unroll
  for (int it = 0; it < 16; ++it) {
    int f = t + it * 256;
    int j = f >> 5;
    int k4 = f & 31;
    *(float4*)&wt[j][k4 * 4] = ((const float4*)W)[f];
  }

  int tj = t >> 3;   // 0..31: j-pair index (8 lanes share one wt row)
  int ns = t & 7;    // 0..7: node-pair within pass
  int j0 = tj * 2;   // dims j0, j0+1, j0+64, j0+65

  for (int p = 0; p < 4; ++p) {
    int nb = node0 + p * GP;
    __syncthreads();
    #pragma unroll
    for (int it = 0; it < 2; ++it) {
      int f = t + it * 256;
      int r = f >> 5;
      int c4 = f & 31;
      int node = nb + r;
      float4 v = make_float4(0.f, 0.f, 0.f, 0.f);
      if (node < n) v = ((const float4*)(x + (size_t)node * D))[c4];
      *(float4*)&zs[r][c4 * 4] = v;
    }
    __syncthreads();

    float acc[2][4] = {};
    #pragma unroll 4
    for (int k = 0; k < D; k += 4) {
      float4 w0 = *(const float4*)&wt[j0][k];
      float4 w1 = *(const float4*)&wt[j0 + 1][k];
      float4 w2 = *(const float4*)&wt[j0 + 64][k];
      float4 w3 = *(const float4*)&wt[j0 + 65][k];
      float4 z0 = *(const float4*)&zs[ns * 2 + 0][k];
      float4 z1 = *(const float4*)&zs[ns * 2 + 1][k];
      acc[0][0] += z0.x * w0.x + z0.y * w0.y + z0.z * w0.z + z0.w * w0.w;
      acc[0][1] += z0.x * w1.x + z0.y * w1.y + z0.z * w1.z + z0.w * w1.w;
      acc[0][2] += z0.x * w2.x + z0.y * w2.y + z0.z * w2.z + z0.w * w2.w;
      acc[0][3] += z0.x * w3.x + z0.y * w3.y + z0.z * w3.z + z0.w * w3.w;
      acc[1][0] += z1.x * w0.x + z1.y * w0.y + z1.z * w0.z + z1.w * w0.w;
      acc[1][1] += z1.x * w1.x + z1.y * w1.y + z1.z * w1.z + z1.w * w1.w;
      acc[1][2] += z1.x * w2.x + z1.y * w2.y + z1.z * w2.z + z1.w * w2.w;
      acc[1][3] += z1.x * w3.x + z1.y * w3.y + z1.z * w3.z + z1.w * w3.w;
    }

    #pragma unroll
    for (int ii = 0; ii < 2; ++ii) {
      int node = nb + ns * 2 + ii;
      if (node < n) {
        uint2 o;
        o.x = (unsigned)f2bf(acc[ii][0]) | ((unsigned)f2bf(acc[ii][2]) << 16);
        o.y = (unsigned)f2bf(acc[ii][1]) | ((unsigned)f2bf(acc[ii][3]) << 16);
        *(uint2*)&y[(size_t)node * 64 + j0] = o;
      }
    }
  }

  // ---------------- Phase B: fill edge chunk ----------------
  int xcc = xcd_id();
  int e0 = blockIdx.x * EPB;
  int e1 = e0 + EPB;
  if (e1 > N_EDGES2_C) e1 = N_EDGES2_C;
  for (int e = e0 + t; e < e1; e += 256) {
    int r, c;
    float v;
    if (e < N_EDGES_C) {
      r = lp_rows[e];
      c = lp_cols[e];
      v = lp_vals[e] * alpha[r];
    } else {
      int i = e - N_EDGES_C;
      r = hp_rows[i];
      c = hp_cols[i];
      v = hp_vals[i] * (1.0f - alpha[r]);
    }
    int p = atomicAdd(&rcursor[xcc * N_NODES_C + r], 1);
    if (p < SCAP) {
      unsigned pk = (unsigned)c | ((unsigned)f2bf(v) << 16);
      pairs[((size_t)r << 7) + (xcc << 4) + p] = pk;
    } else {
      int q = atomicAdd(ofcnt, 1);
      if (q < OFCAP)
        ofl[q] = make_uint2(((unsigned)r << 16) | (unsigned)c,
                            (unsigned)__float_as_int(v));
    }
  }
}

// ---------------------------------------------------------------------------
// Kernel 3: gather — wave per row, register accumulation, no atomics.
// Row's 8 cells (512 B contiguous) ingested with two coalesced 64-lane
// loads; edges broadcast via __shfl (readlane). Fused bias + ReLU.
// ---------------------------------------------------------------------------
__global__ __launch_bounds__(256) void gather_kernel(
    const int* __restrict__ rcursor,     // [NSHARD][N]
    const unsigned* __restrict__ pairs,  // [N][NSHARD][SCAP]
    const unsigned* __restrict__ y,      // [N][64] packed (d, d+64)
    const float* __restrict__ bias,
    const int* __restrict__ ofcnt,
    const uint2* __restrict__ ofl,
    float* __restrict__ out) {
  int row = (int)((blockIdx.x * blockDim.x + threadIdx.x) >> 6);
  int lane = threadIdx.x & 63;
  if (row >= N_NODES_C) return;

  const unsigned* rp = pairs + ((size_t)row << 7);
  unsigned w0 = rp[lane];        // slots 0..63   (cells 0..3)
  unsigned w1 = rp[64 + lane];   // slots 64..127 (cells 4..7)

  float aL = 0.f, aH = 0.f;
  #pragma unroll
  for (int s = 0; s < NSHARD; ++s) {
    int ds = rcursor[(size_t)s * N_NODES_C + row];
    if (ds > SCAP) ds = SCAP;
    unsigned wsrc = (s < 4) ? w0 : w1;
    int base = (s & 3) << 4;
    int p = 0;
    for (; p + 1 < ds; p += 2) {
      unsigned pk0 = (unsigned)__shfl((int)wsrc, base + p);
      unsigned pk1 = (unsigned)__shfl((int)wsrc, base + p + 1);
      unsigned u0 = y[(size_t)(pk0 & 0xffffu) * 64 + lane];
      unsigned u1 = y[(size_t)(pk1 & 0xffffu) * 64 + lane];
      float v0 = bf_hi(pk0);
      float v1 = bf_hi(pk1);
      aL += v0 * bf_lo(u0) + v1 * bf_lo(u1);
      aH += v0 * bf_hi(u0) + v1 * bf_hi(u1);
    }
    if (p < ds) {
      unsigned pk = (unsigned)__shfl((int)wsrc, base + p);
      unsigned u = y[(size_t)(pk & 0xffffu) * 64 + lane];
      aL += bf_hi(pk) * bf_lo(u);
      aH += bf_hi(pk) * bf_hi(u);
    }
  }

  // overflow entries (expected 0)
  int nof = *ofcnt;
  if (nof > OFCAP) nof = OFCAP;
  for (int i = 0; i < nof; ++i) {
    uint2 o = ofl[i];
    if ((int)(o.x >> 16) == row) {
      unsigned u = y[(size_t)(o.x & 0xffffu) * 64 + lane];
      float v = __int_as_float((int)o.y);
      aL += v * bf_lo(u);
      aH += v * bf_hi(u);
    }
  }

  out[(size_t)row * D + lane] = fmaxf(aL + bias[lane], 0.0f);
  out[(size_t)row * D + lane + 64] = fmaxf(aH + bias[lane + 64], 0.0f);
}

extern "C" void kernel_launch(void* const* d_in, const int* in_sizes, int n_in,
                              void* d_out, int out_size, void* d_ws, size_t ws_size,
                              hipStream_t stream) {
  const float* x = (const float*)d_in[0];
  const int* lp_rows = (const int*)d_in[1];
  const int* lp_cols = (const int*)d_in[2];
  const float* lp_vals = (const float*)d_in[3];
  const int* hp_rows = (const int*)d_in[4];
  const int* hp_cols = (const int*)d_in[5];
  const float* hp_vals = (const float*)d_in[6];
  const float* alpha_w = (const float*)d_in[7];
  const float* alpha_b = (const float*)d_in[8];
  const float* W = (const float*)d_in[9];
  const float* bias = (const float*)d_in[10];

  float* out = (float*)d_out;                      // [N, 128]
  float* alpha_out = out + (size_t)N_NODES_C * D;  // [N, 1] output tail

  char* ws = (char*)d_ws;
  unsigned* y = (unsigned*)ws;   ws += (size_t)N_NODES_C * 64 * 4;          // 12.8 MB
  float* alpha_ws = (float*)ws;  ws += 200192;
  int* rcursor = (int*)ws;       ws += (size_t)N_NODES_C * NSHARD * 4;      // 1.6 MB
  int* ofcnt = (int*)ws;         ws += 256;
  uint2* ofl = (uint2*)ws;       ws += (size_t)OFCAP * 8;                   // 32 KB
  unsigned* pairs = (unsigned*)ws;
  ws += (size_t)N_NODES_C * NSHARD * SCAP * 4;                              // 25.6 MB

  // zero cursors + overflow counter in one memset (contiguous)
  hipMemsetAsync(rcursor, 0,
                 (size_t)N_NODES_C * NSHARD * sizeof(int) + 256, stream);

  alpha_kernel<<<(N_NODES_C + 3) / 4, 256, 0, stream>>>(
      x, alpha_w, alpha_b, alpha_out, alpha_ws, N_NODES_C);

  gemm_fill_kernel<<<GRID, 256, 0, stream>>>(
      x, W, y,
      lp_rows, lp_cols, lp_vals, hp_rows, hp_cols, hp_vals,
      alpha_ws, rcursor, pairs, ofcnt, ofl, N_NODES_C);

  gather_kernel<<<(N_NODES_C * 64 + 255) / 256, 256, 0, stream>>>(
      rcursor, pairs, (const unsigned*)y, bias, ofcnt, ofl, out);
}

// Round 14
// 300.462 us; speedup vs baseline: 1.1440x; 1.0194x over previous
//
#include <hip/hip_runtime.h>

#define N_NODES_C 50000
#define N_EDGES_C 800000
#define N_EDGES2_C (2 * N_EDGES_C)
#define D 128
#define NSHARD 8
#define SCAP 16    // slots per (row,xcd) cell = one 64 B line
#define OFCAP 4096 // overflow list capacity (expected use ~0)

#define GNODES 64
#define GP 16
#define LDP 132
#define GRID ((N_NODES_C + GNODES - 1) / GNODES)          // 782
#define EPB ((N_EDGES2_C + GRID - 1) / GRID)              // 2047

static __device__ __forceinline__ unsigned short f2bf(float f) {
  unsigned u = __float_as_uint(f);
  u += 0x7fff + ((u >> 16) & 1);  // round-to-nearest-even
  return (unsigned short)(u >> 16);
}
static __device__ __forceinline__ float bf_lo(unsigned u) {
  return __uint_as_float(u << 16);
}
static __device__ __forceinline__ float bf_hi(unsigned u) {
  return __uint_as_float(u & 0xffff0000u);
}

// Physical XCD id (0..7), wave-uniform; steers L2 locality only.
static __device__ __forceinline__ int xcd_id() {
  int v;
  asm volatile("s_getreg_b32 %0, hwreg(HW_REG_XCC_ID, 0, 4)" : "=s"(v));
  return v & (NSHARD - 1);
}

// ---------------------------------------------------------------------------
// Kernel 1: alpha[i] = sigmoid(dot(x[i], alpha_w) + alpha_b), wave per node.
// ---------------------------------------------------------------------------
__global__ __launch_bounds__(256) void alpha_kernel(
    const float* __restrict__ x,
    const float* __restrict__ aw,
    const float* __restrict__ ab,
    float* __restrict__ alpha_out,
    float* __restrict__ alpha_ws,
    int n) {
  int wave = (int)((blockIdx.x * blockDim.x + threadIdx.x) >> 6);
  int lane = threadIdx.x & 63;
  if (wave >= n) return;
  const float* xr = x + (size_t)wave * D;
  float s = xr[lane] * aw[lane] + xr[lane + 64] * aw[lane + 64];
  #pragma unroll
  for (int off = 32; off > 0; off >>= 1)
    s += __shfl_down(s, off);
  if (lane == 0) {
    float a = 1.0f / (1.0f + __expf(-(s + ab[0])));
    alpha_out[wave] = a;
    alpha_ws[wave] = a;
  }
}

// ---------------------------------------------------------------------------
// Kernel 2 (FUSED): phase A = gemm_y (j split into 2 halves -> wt LDS
// halved -> 42.2 KB total -> 3 blocks/CU), phase B = fill edge chunk.
// y packing: word q of a row = (bf16 dim 2q, bf16 dim 2q+1) — each j-half
// produces complete words. Lane map tj=t>>3, ns=t&7 keeps LDS reads
// conflict-free (verified R12: 6.4M -> 0).
// ---------------------------------------------------------------------------
__global__ __launch_bounds__(256) void gemm_fill_kernel(
    const float* __restrict__ x,
    const float* __restrict__ W,
    unsigned* __restrict__ y,        // [N][64] packed words
    const int* __restrict__ lp_rows, const int* __restrict__ lp_cols,
    const float* __restrict__ lp_vals,
    const int* __restrict__ hp_rows, const int* __restrict__ hp_cols,
    const float* __restrict__ hp_vals,
    const float* __restrict__ alpha,
    int* __restrict__ rcursor,       // [NSHARD][N], zeroed before launch
    unsigned* __restrict__ pairs,    // [N][NSHARD][SCAP]
    int* __restrict__ ofcnt,
    uint2* __restrict__ ofl,
    int n) {
  __shared__ float wt[64][LDP];   // one j-half of W: 33.8 KB
  __shared__ float zs[GP][LDP];   // 8.4 KB

  int t = threadIdx.x;
  int node0 = blockIdx.x * GNODES;

  int tj = t >> 3;   // 0..31: j-pair within half (8 lanes share one wt row)
  int ns = t & 7;    // 0..7: node-pair within pass
  int jl = tj * 2;   // local W row in this half

  // ---------------- Phase A: gemm tile, two j-halves ----------------
  for (int jh = 0; jh < 2; ++jh) {
    __syncthreads();  // prior half's compute done before wt overwrite
    // stage W rows [jh*64, jh*64+64): 2048 float4, 8 per thread
    #pragma unroll
    for (int it = 0; it < 8; ++it) {
      int f = t + it * 256;
      int j = f >> 5;
      int k4 = f & 31;
      *(float4*)&wt[j][k4 * 4] =
          ((const float4*)W)[(size_t)(jh * 64 + j) * 32 + k4];
    }

    for (int p = 0; p < 4; ++p) {
      int nb = node0 + p * GP;
      __syncthreads();  // wt staged / prior compute done reading zs
      #pragma unroll
      for (int it = 0; it < 2; ++it) {
        int f = t + it * 256;
        int r = f >> 5;
        int c4 = f & 31;
        int node = nb + r;
        float4 v = make_float4(0.f, 0.f, 0.f, 0.f);
        if (node < n) v = ((const float4*)(x + (size_t)node * D))[c4];
        *(float4*)&zs[r][c4 * 4] = v;
      }
      __syncthreads();

      float acc[2][2] = {};
      #pragma unroll 4
      for (int k = 0; k < D; k += 4) {
        float4 w0 = *(const float4*)&wt[jl][k];
        float4 w1 = *(const float4*)&wt[jl + 1][k];
        float4 z0 = *(const float4*)&zs[ns * 2 + 0][k];
        float4 z1 = *(const float4*)&zs[ns * 2 + 1][k];
        acc[0][0] += z0.x * w0.x + z0.y * w0.y + z0.z * w0.z + z0.w * w0.w;
        acc[0][1] += z0.x * w1.x + z0.y * w1.y + z0.z * w1.z + z0.w * w1.w;
        acc[1][0] += z1.x * w0.x + z1.y * w0.y + z1.z * w0.z + z1.w * w0.w;
        acc[1][1] += z1.x * w1.x + z1.y * w1.y + z1.z * w1.z + z1.w * w1.w;
      }

      #pragma unroll
      for (int ii = 0; ii < 2; ++ii) {
        int node = nb + ns * 2 + ii;
        if (node < n) {
          unsigned o = (unsigned)f2bf(acc[ii][0]) |
                       ((unsigned)f2bf(acc[ii][1]) << 16);
          y[(size_t)node * 64 + jh * 32 + tj] = o;
        }
      }
    }
  }

  // ---------------- Phase B: fill edge chunk ----------------
  int xcc = xcd_id();
  int e0 = blockIdx.x * EPB;
  int e1 = e0 + EPB;
  if (e1 > N_EDGES2_C) e1 = N_EDGES2_C;
  for (int e = e0 + t; e < e1; e += 256) {
    int r, c;
    float v;
    if (e < N_EDGES_C) {
      r = lp_rows[e];
      c = lp_cols[e];
      v = lp_vals[e] * alpha[r];
    } else {
      int i = e - N_EDGES_C;
      r = hp_rows[i];
      c = hp_cols[i];
      v = hp_vals[i] * (1.0f - alpha[r]);
    }
    int p = atomicAdd(&rcursor[xcc * N_NODES_C + r], 1);
    if (p < SCAP) {
      unsigned pk = (unsigned)c | ((unsigned)f2bf(v) << 16);
      pairs[((size_t)r << 7) + (xcc << 4) + p] = pk;
    } else {
      int q = atomicAdd(ofcnt, 1);
      if (q < OFCAP)
        ofl[q] = make_uint2(((unsigned)r << 16) | (unsigned)c,
                            (unsigned)__float_as_int(v));
    }
  }
}

// ---------------------------------------------------------------------------
// Kernel 3: gather — TWO waves per row (each owns 4 of the 8 cells) to
// halve the per-wave dependent y-load chain and double wave-level latency
// hiding. Partials combined via 2 KB LDS. Lane owns dims (2l, 2l+1) ->
// float2 bias/out. Register accumulation, no atomics.
// ---------------------------------------------------------------------------
__global__ __launch_bounds__(256) void gather_kernel(
    const int* __restrict__ rcursor,     // [NSHARD][N]
    const unsigned* __restrict__ pairs,  // [N][NSHARD][SCAP]
    const unsigned* __restrict__ y,      // [N][64], word q = dims (2q,2q+1)
    const float* __restrict__ bias,
    const int* __restrict__ ofcnt,
    const uint2* __restrict__ ofl,
    float* __restrict__ out) {
  __shared__ float2 part[4][64];
  int t = threadIdx.x;
  int w = t >> 6;      // wave 0..3
  int lane = t & 63;
  int row = blockIdx.x * 2 + (w >> 1);
  int half = w & 1;    // cells [half*4, half*4+4)

  float aL = 0.f, aH = 0.f;
  if (row < N_NODES_C) {
    const unsigned* rp = pairs + ((size_t)row << 7) + (half << 6);
    unsigned wsrc = rp[lane];  // this half's 64 slots (4 cells)

    #pragma unroll
    for (int sc = 0; sc < 4; ++sc) {
      int s = half * 4 + sc;
      int ds = rcursor[(size_t)s * N_NODES_C + row];
      if (ds > SCAP) ds = SCAP;
      int base = sc << 4;
      int p = 0;
      for (; p + 1 < ds; p += 2) {
        unsigned pk0 = (unsigned)__shfl((int)wsrc, base + p);
        unsigned pk1 = (unsigned)__shfl((int)wsrc, base + p + 1);
        unsigned u0 = y[(size_t)(pk0 & 0xffffu) * 64 + lane];
        unsigned u1 = y[(size_t)(pk1 & 0xffffu) * 64 + lane];
        float v0 = bf_hi(pk0);
        float v1 = bf_hi(pk1);
        aL += v0 * bf_lo(u0) + v1 * bf_lo(u1);
        aH += v0 * bf_hi(u0) + v1 * bf_hi(u1);
      }
      if (p < ds) {
        unsigned pk = (unsigned)__shfl((int)wsrc, base + p);
        unsigned u = y[(size_t)(pk & 0xffffu) * 64 + lane];
        aL += bf_hi(pk) * bf_lo(u);
        aH += bf_hi(pk) * bf_hi(u);
      }
    }

    // overflow entries (expected 0): half 0 only
    if (half == 0) {
      int nof = *ofcnt;
      if (nof > OFCAP) nof = OFCAP;
      for (int i = 0; i < nof; ++i) {
        uint2 o = ofl[i];
        if ((int)(o.x >> 16) == row) {
          unsigned u = y[(size_t)(o.x & 0xffffu) * 64 + lane];
          float v = __int_as_float((int)o.y);
          aL += v * bf_lo(u);
          aH += v * bf_hi(u);
        }
      }
    }
  }
  part[w][lane] = make_float2(aL, aH);
  __syncthreads();

  if (half == 0 && row < N_NODES_C) {
    float2 a = part[w][lane];
    float2 b = part[w + 1][lane];
    float2 bv = *(const float2*)&bias[lane * 2];
    float2 o;
    o.x = fmaxf(a.x + b.x + bv.x, 0.0f);
    o.y = fmaxf(a.y + b.y + bv.y, 0.0f);
    *(float2*)&out[(size_t)row * D + lane * 2] = o;
  }
}

extern "C" void kernel_launch(void* const* d_in, const int* in_sizes, int n_in,
                              void* d_out, int out_size, void* d_ws, size_t ws_size,
                              hipStream_t stream) {
  const float* x = (const float*)d_in[0];
  const int* lp_rows = (const int*)d_in[1];
  const int* lp_cols = (const int*)d_in[2];
  const float* lp_vals = (const float*)d_in[3];
  const int* hp_rows = (const int*)d_in[4];
  const int* hp_cols = (const int*)d_in[5];
  const float* hp_vals = (const float*)d_in[6];
  const float* alpha_w = (const float*)d_in[7];
  const float* alpha_b = (const float*)d_in[8];
  const float* W = (const float*)d_in[9];
  const float* bias = (const float*)d_in[10];

  float* out = (float*)d_out;                      // [N, 128]
  float* alpha_out = out + (size_t)N_NODES_C * D;  // [N, 1] output tail

  char* ws = (char*)d_ws;
  unsigned* y = (unsigned*)ws;   ws += (size_t)N_NODES_C * 64 * 4;          // 12.8 MB
  float* alpha_ws = (float*)ws;  ws += 200192;
  int* rcursor = (int*)ws;       ws += (size_t)N_NODES_C * NSHARD * 4;      // 1.6 MB
  int* ofcnt = (int*)ws;         ws += 256;
  uint2* ofl = (uint2*)ws;       ws += (size_t)OFCAP * 8;                   // 32 KB
  unsigned* pairs = (unsigned*)ws;
  ws += (size_t)N_NODES_C * NSHARD * SCAP * 4;                              // 25.6 MB

  // zero cursors + overflow counter in one memset (contiguous)
  hipMemsetAsync(rcursor, 0,
                 (size_t)N_NODES_C * NSHARD * sizeof(int) + 256, stream);

  alpha_kernel<<<(N_NODES_C + 3) / 4, 256, 0, stream>>>(
      x, alpha_w, alpha_b, alpha_out, alpha_ws, N_NODES_C);

  gemm_fill_kernel<<<GRID, 256, 0, stream>>>(
      x, W, y,
      lp_rows, lp_cols, lp_vals, hp_rows, hp_cols, hp_vals,
      alpha_ws, rcursor, pairs, ofcnt, ofl, N_NODES_C);

  gather_kernel<<<(N_NODES_C + 1) / 2, 256, 0, stream>>>(
      rcursor, pairs, (const unsigned*)y, bias, ofcnt, ofl, out);
}